// Round 7
// baseline (221.167 us; speedup 1.0000x reference)
//
#include <hip/hip_runtime.h>
#include <hip/hip_fp16.h>
#include <math.h>

#define B_  8
#define H_  64
#define W_  64
#define C_  128
#define F_  256
#define NOC 27

typedef float    f32x4 __attribute__((ext_vector_type(4)));
typedef _Float16 f16x8 __attribute__((ext_vector_type(8)));

// ws layout (float units):
//   woffT : f16[9][32][128]   @ 0         (73728 B)
//   filtT : f16[9][256][128]  @ 32768     (589824 B)
//   wi32  : float[32768][32]  @ 180224    (4 MB)
//   inh   : f16[8][64][64][128] @ 1228800 (8.4 MB)   total ws ~13.3 MB
#define FILTT_OFF_F 32768
#define WI32_OFF_F  180224
#define INH_OFF_F   1228800

static __device__ __forceinline__ unsigned pkh2(float a, float b) {
    __half2 h = __floats2half2_rn(a, b);
    union { __half2 h2; unsigned u; } cv; cv.h2 = h;
    return cv.u;
}

// ---------------------------------------------------------------- repack (f32 -> f16)
__global__ __launch_bounds__(256) void repack(const float* __restrict__ kofs,
                                              const float* __restrict__ filt,
                                              unsigned short* __restrict__ woffT,
                                              unsigned short* __restrict__ filtT) {
    int idx = blockIdx.x * 256 + threadIdx.x;
    if (idx < 9 * 32 * 128) {
        int tap = idx >> 12;
        int r   = idx & 4095;
        int oc  = r >> 7;
        int c   = r & 127;
        float v = (oc < NOC) ? kofs[(tap * C_ + c) * NOC + oc] : 0.f;
        union { __half h; unsigned short u; } cv; cv.h = __float2half(v);
        woffT[idx] = cv.u;
        return;
    }
    int idx2 = idx - 9 * 32 * 128;
    if (idx2 < 9 * 256 * 128) {
        int tap = idx2 / 32768;
        int r   = idx2 & 32767;
        int f   = r >> 7;
        int c   = r & 127;
        float v = filt[(tap * C_ + c) * F_ + f];
        union { __half h; unsigned short u; } cv; cv.h = __float2half(v);
        filtT[idx2] = cv.u;
    }
}

// ---------------------------------------------------------------- input f32 -> f16 copy
__global__ __launch_bounds__(256) void conv_f16(const float* __restrict__ in,
                                                unsigned short* __restrict__ inh) {
    int gid = blockIdx.x * 256 + threadIdx.x;    // 262144 threads x 16 floats
    const float4* ip = reinterpret_cast<const float4*>(in) + (size_t)gid * 4;
    float4 a = ip[0], b = ip[1], c = ip[2], d = ip[3];
    uint4 r0 = make_uint4(pkh2(a.x, a.y), pkh2(a.z, a.w), pkh2(b.x, b.y), pkh2(b.z, b.w));
    uint4 r1 = make_uint4(pkh2(c.x, c.y), pkh2(c.z, c.w), pkh2(d.x, d.y), pkh2(d.z, d.w));
    uint4* op = reinterpret_cast<uint4*>(inh) + (size_t)gid * 2;
    op[0] = r0; op[1] = r1;
}

// ---------------------------------------------------------------- offset conv (f16 MFMA)
__global__ __launch_bounds__(256) void offset_conv_mfma(const unsigned short* __restrict__ inh,
                                                        const unsigned short* __restrict__ woffT,
                                                        const float* __restrict__ bias,
                                                        float* __restrict__ wi32) {
    __shared__ __align__(16) unsigned char win[3 * 66 * 256];   // 50688 B

    int t    = threadIdx.x;
    int bid  = blockIdx.x;
    int lg   = ((bid & 7) << 6) | (bid >> 3);       // 512 = 8*64
    int bb   = lg >> 6;
    int hh   = lg & 63;
    int pix0 = lg << 6;

    for (int idx = t; idx < 3 * 66 * 16; idx += 256) {
        int ky = idx / (66 * 16);
        int r  = idx % (66 * 16);
        int xi = r >> 4;
        int c8 = r & 15;
        int y  = hh + ky - 1;
        int x  = xi - 1;
        uint4 v = make_uint4(0u, 0u, 0u, 0u);
        if ((unsigned)y < 64u && (unsigned)x < 64u)
            v = *(const uint4*)((const char*)inh +
                    ((size_t)(((bb << 6) + y) * 64 + x) << 8) + (c8 << 4));
        *(uint4*)(win + ky * 16896 + xi * 256 + ((c8 << 4) ^ ((xi & 7) << 4))) = v;
    }
    __syncthreads();

    int lane = t & 63, wv = t >> 6;
    int row  = lane & 15, kg = lane >> 4;
    int px0  = wv << 4;

    f32x4 z = {0.f, 0.f, 0.f, 0.f};
    f32x4 acc[2] = {z, z};

    for (int tap = 0; tap < 9; ++tap) {
        int ky = tap / 3, kx = tap - ky * 3;
        int xi = px0 + row + kx;
        const unsigned char* arow = win + ky * 16896 + xi * 256;
        int sw = (xi & 7) << 4;
        const unsigned short* bp = woffT + (size_t)tap * 4096 + (size_t)row * 128 + kg * 8;
        #pragma unroll
        for (int ks = 0; ks < 4; ++ks) {
            f16x8 a  = *(const f16x8*)(arow + ((ks * 64 + kg * 16) ^ sw));
            f16x8 b0 = *(const f16x8*)(bp + ks * 32);
            f16x8 b1 = *(const f16x8*)(bp + 2048 + ks * 32);
            acc[0] = __builtin_amdgcn_mfma_f32_16x16x32_f16(a, b0, acc[0], 0, 0, 0);
            acc[1] = __builtin_amdgcn_mfma_f32_16x16x32_f16(a, b1, acc[1], 0, 0, 0);
        }
    }

    #pragma unroll
    for (int n = 0; n < 2; ++n) {
        int oc = n * 16 + row;
        float bv = (oc < NOC) ? bias[oc] : 0.f;
        #pragma unroll
        for (int r = 0; r < 4; ++r) {
            int px = px0 + kg * 4 + r;
            wi32[(size_t)(pix0 + px) * 32 + oc] = acc[n][r] + bv;
        }
    }
}

// ---------------------------------------------------------------- main deform conv
// block = 32 px x 256 F, 256 thr / 4 waves (wave wc: F [64wc,64wc+64), all 32 px).
// Register-direct A: each lane gathers its own MFMA A-fragments from the f16
// image (L2-resident via XCD swizzle). No A-LDS, no K-loop barriers.
__global__ __launch_bounds__(256, 4) void deform_reg(const unsigned short* __restrict__ inh,
                                                     const unsigned short* __restrict__ filtT,
                                                     const float* __restrict__ wi32,
                                                     float* __restrict__ out) {
    __shared__ __align__(16) uint4 offs[32][9];   // 4 corner byte-offsets into inh
    __shared__ __align__(16) uint2 wgts[32][9];   // 4 f16 weights (mask+valid folded)

    int t    = threadIdx.x;
    int bid  = blockIdx.x;
    int lg   = ((bid & 7) << 7) | (bid >> 3);     // 1024 = 8*128, XCD-bijective
    int bb   = lg >> 7;
    int rem  = lg & 127;
    int hh   = rem >> 1;
    int w0   = (rem & 1) << 5;
    int pix0 = lg << 5;

    // ---- per-(px,tap) sampling params (288 items)
    for (int it = t; it < 288; it += 256) {
        int tap = it >> 5;
        int px  = it & 31;
        const float* wp = wi32 + (size_t)(pix0 + px) * 32;
        float o1 = wp[tap], o2 = wp[9 + tap], mm = wp[18 + tap];
        float mask = 1.f / (1.f + __expf(-mm));
        int ky = tap / 3, kx = tap - ky * 3;
        float py  = (float)(hh - 1 + ky) + o1;
        float pxx = (float)(w0 + px - 1 + kx) + o2;
        float y0f = floorf(py), x0f = floorf(pxx);
        float wy1 = py - y0f,  wy0 = 1.f - wy1;
        float wx1 = pxx - x0f, wx0 = 1.f - wx1;
        float vy0 = (y0f >=  0.f && y0f <= 63.f) ? 1.f : 0.f;
        float vy1 = (y0f >= -1.f && y0f <= 62.f) ? 1.f : 0.f;
        float vx0 = (x0f >=  0.f && x0f <= 63.f) ? 1.f : 0.f;
        float vx1 = (x0f >= -1.f && x0f <= 62.f) ? 1.f : 0.f;
        int y0 = (int)fminf(fmaxf(y0f,       0.f), 63.f);
        int y1 = (int)fminf(fmaxf(y0f + 1.f, 0.f), 63.f);
        int x0 = (int)fminf(fmaxf(x0f,       0.f), 63.f);
        int x1 = (int)fminf(fmaxf(x0f + 1.f, 0.f), 63.f);
        int base = bb << 12;
        offs[px][tap] = make_uint4((unsigned)((base + (y0 << 6) + x0) << 8),
                                   (unsigned)((base + (y0 << 6) + x1) << 8),
                                   (unsigned)((base + (y1 << 6) + x0) << 8),
                                   (unsigned)((base + (y1 << 6) + x1) << 8));
        wgts[px][tap] = make_uint2(pkh2(wy0 * wx0 * mask * vy0 * vx0,
                                        wy0 * wx1 * mask * vy0 * vx1),
                                   pkh2(wy1 * wx0 * mask * vy1 * vx0,
                                        wy1 * wx1 * mask * vy1 * vx1));
    }
    __syncthreads();          // the only barrier

    int lane = t & 63, wc = t >> 6;
    int arow = lane & 15;     // px within 16 / B f-col
    int kq   = lane >> 4;     // 8-ch sub-chunk

    const char* ih = (const char*)inh;
    const char* fb = (const char*)filtT + ((wc << 6) + arow) * 256 + (kq << 4);

    f32x4 z = {0.f, 0.f, 0.f, 0.f};
    f32x4 acc[2][4];
    #pragma unroll
    for (int m = 0; m < 2; ++m)
        #pragma unroll
        for (int n = 0; n < 4; ++n) acc[m][n] = z;

    #pragma unroll 1
    for (int tap = 0; tap < 9; ++tap) {
        union AU { uint4 u; __half2 h[4]; f16x8 v; };
        f16x8 a[2][4];
        #pragma unroll
        for (int m = 0; m < 2; ++m) {
            int px = (m << 4) + arow;
            uint4 O  = offs[px][tap];
            uint2 Wp = wgts[px][tap];
            union { unsigned u; __half2 h; } w00, w01, w10, w11;
            w00.u = (Wp.x & 0xFFFFu) * 0x10001u;
            w01.u = (Wp.x >> 16)     * 0x10001u;
            w10.u = (Wp.y & 0xFFFFu) * 0x10001u;
            w11.u = (Wp.y >> 16)     * 0x10001u;
            #pragma unroll
            for (int ks = 0; ks < 4; ++ks) {
                int cb = (ks << 6) + (kq << 4);
                AU c00, c01, c10, c11, s;
                c00.u = *(const uint4*)(ih + O.x + cb);
                c01.u = *(const uint4*)(ih + O.y + cb);
                c10.u = *(const uint4*)(ih + O.z + cb);
                c11.u = *(const uint4*)(ih + O.w + cb);
                #pragma unroll
                for (int j = 0; j < 4; ++j) {
                    __half2 sj = __hmul2(c00.h[j], w00.h);
                    sj = __hfma2(c01.h[j], w01.h, sj);
                    sj = __hfma2(c10.h[j], w10.h, sj);
                    s.h[j] = __hfma2(c11.h[j], w11.h, sj);
                }
                a[m][ks] = s.v;
            }
        }
        // ---- B + MFMA (B is L2/L1-hot, contiguous 64B per row)
        const char* ft = fb + (size_t)tap * 65536;
        __builtin_amdgcn_s_setprio(1);
        #pragma unroll
        for (int n = 0; n < 4; ++n) {
            #pragma unroll
            for (int ks = 0; ks < 4; ++ks) {
                f16x8 bv = *(const f16x8*)(ft + n * 4096 + (ks << 6));
                acc[0][n] = __builtin_amdgcn_mfma_f32_16x16x32_f16(a[0][ks], bv, acc[0][n], 0, 0, 0);
                acc[1][n] = __builtin_amdgcn_mfma_f32_16x16x32_f16(a[1][ks], bv, acc[1][n], 0, 0, 0);
            }
        }
        __builtin_amdgcn_s_setprio(0);
    }

    // ---- epilogue: D row px = 4*kq + r, col f = arow
    #pragma unroll
    for (int m = 0; m < 2; ++m)
        #pragma unroll
        for (int r = 0; r < 4; ++r) {
            int px = (m << 4) + (kq << 2) + r;
            float* op = out + (size_t)(pix0 + px) * 256 + (wc << 6) + arow;
            op[0]  = acc[m][0][r];
            op[16] = acc[m][1][r];
            op[32] = acc[m][2][r];
            op[48] = acc[m][3][r];
        }
}

// ---------------------------------------------------------------- launch
extern "C" void kernel_launch(void* const* d_in, const int* in_sizes, int n_in,
                              void* d_out, int out_size, void* d_ws, size_t ws_size,
                              hipStream_t stream) {
    const float* in   = (const float*)d_in[0];
    const float* kofs = (const float*)d_in[1];
    const float* bias = (const float*)d_in[2];
    const float* filt = (const float*)d_in[3];
    float* out = (float*)d_out;
    float* ws  = (float*)d_ws;

    unsigned short* woffT = (unsigned short*)ws;
    unsigned short* filtT = (unsigned short*)(ws + FILTT_OFF_F);
    float*          wi32  = ws + WI32_OFF_F;
    unsigned short* inh   = (unsigned short*)(ws + INH_OFF_F);

    hipLaunchKernelGGL(repack, dim3(1296), dim3(256), 0, stream, kofs, filt, woffT, filtT);
    hipLaunchKernelGGL(conv_f16, dim3(1024), dim3(256), 0, stream, in, inh);
    hipLaunchKernelGGL(offset_conv_mfma, dim3(512), dim3(256), 0, stream, inh, woffT, bias, wi32);
    hipLaunchKernelGGL(deform_reg, dim3(1024), dim3(256), 0, stream, inh, filtT, wi32, out);
}

// Round 8
// 107.444 us; speedup vs baseline: 2.0584x; 2.0584x over previous
//
#include <hip/hip_runtime.h>
#include <hip/hip_fp16.h>
#include <math.h>

#define B_  8
#define H_  64
#define W_  64
#define C_  128
#define F_  256
#define NOC 27

typedef float    f32x4 __attribute__((ext_vector_type(4)));
typedef _Float16 f16x8 __attribute__((ext_vector_type(8)));

// ws layout (float units):
//   woffT  : f16[9][32][128]     @ 0        (73728 B)
//   filtT2 : f16[256][1152]      @ 32768    (589824 B)   [f][k], k=tap*128+c
//   wi32   : float[32768][32]    @ 180224   (4 MB)
//   inh    : f16[8][64][64][128] @ 1228800  (8.4 MB)
//   Aim    : f16[16384][1152]    @ 3325952  (37.75 MB)   im2col half-image buffer
// total ~48.7 MB of d_ws
#define FILTT_OFF_F 32768
#define WI32_OFF_F  180224
#define INH_OFF_F   1228800
#define AIM_OFF_F   3325952

static __device__ __forceinline__ unsigned pkh2(float a, float b) {
    __half2 h = __floats2half2_rn(a, b);
    union { __half2 h2; unsigned u; } cv; cv.h2 = h;
    return cv.u;
}

static __device__ __forceinline__ void async16(void* lds, const void* g) {
    __builtin_amdgcn_global_load_lds(
        (const __attribute__((address_space(1))) unsigned int*)g,
        (__attribute__((address_space(3))) unsigned int*)lds, 16, 0, 0);
}

// ---------------------------------------------------------------- repack (f32 -> f16)
__global__ __launch_bounds__(256) void repack(const float* __restrict__ kofs,
                                              const float* __restrict__ filt,
                                              unsigned short* __restrict__ woffT,
                                              unsigned short* __restrict__ filtT2) {
    int idx = blockIdx.x * 256 + threadIdx.x;
    if (idx < 9 * 32 * 128) {
        int tap = idx >> 12;
        int r   = idx & 4095;
        int oc  = r >> 7;
        int c   = r & 127;
        float v = (oc < NOC) ? kofs[(tap * C_ + c) * NOC + oc] : 0.f;
        union { __half h; unsigned short u; } cv; cv.h = __float2half(v);
        woffT[idx] = cv.u;
        return;
    }
    int idx2 = idx - 9 * 32 * 128;
    if (idx2 < 9 * 256 * 128) {
        int tap = idx2 / 32768;
        int r   = idx2 & 32767;
        int f   = r >> 7;
        int c   = r & 127;
        float v = filt[(tap * C_ + c) * F_ + f];
        union { __half h; unsigned short u; } cv; cv.h = __float2half(v);
        filtT2[(size_t)f * 1152 + tap * 128 + c] = cv.u;
    }
}

// ---------------------------------------------------------------- input f32 -> f16
__global__ __launch_bounds__(256) void conv_f16(const float* __restrict__ in,
                                                unsigned short* __restrict__ inh) {
    int gid = blockIdx.x * 256 + threadIdx.x;
    const float4* ip = reinterpret_cast<const float4*>(in) + (size_t)gid * 4;
    float4 a = ip[0], b = ip[1], c = ip[2], d = ip[3];
    uint4 r0 = make_uint4(pkh2(a.x, a.y), pkh2(a.z, a.w), pkh2(b.x, b.y), pkh2(b.z, b.w));
    uint4 r1 = make_uint4(pkh2(c.x, c.y), pkh2(c.z, c.w), pkh2(d.x, d.y), pkh2(d.z, d.w));
    uint4* op = reinterpret_cast<uint4*>(inh) + (size_t)gid * 2;
    op[0] = r0; op[1] = r1;
}

// ---------------------------------------------------------------- offset conv (f16 MFMA)
__global__ __launch_bounds__(256) void offset_conv_mfma(const unsigned short* __restrict__ inh,
                                                        const unsigned short* __restrict__ woffT,
                                                        const float* __restrict__ bias,
                                                        float* __restrict__ wi32) {
    __shared__ __align__(16) unsigned char win[3 * 66 * 256];   // 50688 B

    int t    = threadIdx.x;
    int bid  = blockIdx.x;
    int lg   = ((bid & 7) << 6) | (bid >> 3);       // 512 = 8*64
    int bb   = lg >> 6;
    int hh   = lg & 63;
    int pix0 = lg << 6;

    for (int idx = t; idx < 3 * 66 * 16; idx += 256) {
        int ky = idx / (66 * 16);
        int r  = idx % (66 * 16);
        int xi = r >> 4;
        int c8 = r & 15;
        int y  = hh + ky - 1;
        int x  = xi - 1;
        uint4 v = make_uint4(0u, 0u, 0u, 0u);
        if ((unsigned)y < 64u && (unsigned)x < 64u)
            v = *(const uint4*)((const char*)inh +
                    ((size_t)(((bb << 6) + y) * 64 + x) << 8) + (c8 << 4));
        *(uint4*)(win + ky * 16896 + xi * 256 + ((c8 << 4) ^ ((xi & 7) << 4))) = v;
    }
    __syncthreads();

    int lane = t & 63, wv = t >> 6;
    int row  = lane & 15, kg = lane >> 4;
    int px0  = wv << 4;

    f32x4 z = {0.f, 0.f, 0.f, 0.f};
    f32x4 acc[2] = {z, z};

    for (int tap = 0; tap < 9; ++tap) {
        int ky = tap / 3, kx = tap - ky * 3;
        int xi = px0 + row + kx;
        const unsigned char* arow = win + ky * 16896 + xi * 256;
        int sw = (xi & 7) << 4;
        const unsigned short* bp = woffT + (size_t)tap * 4096 + (size_t)row * 128 + kg * 8;
        #pragma unroll
        for (int ks = 0; ks < 4; ++ks) {
            f16x8 a  = *(const f16x8*)(arow + ((ks * 64 + kg * 16) ^ sw));
            f16x8 b0 = *(const f16x8*)(bp + ks * 32);
            f16x8 b1 = *(const f16x8*)(bp + 2048 + ks * 32);
            acc[0] = __builtin_amdgcn_mfma_f32_16x16x32_f16(a, b0, acc[0], 0, 0, 0);
            acc[1] = __builtin_amdgcn_mfma_f32_16x16x32_f16(a, b1, acc[1], 0, 0, 0);
        }
    }

    #pragma unroll
    for (int n = 0; n < 2; ++n) {
        int oc = n * 16 + row;
        float bv = (oc < NOC) ? bias[oc] : 0.f;
        #pragma unroll
        for (int r = 0; r < 4; ++r) {
            int px = px0 + kg * 4 + r;
            wi32[(size_t)(pix0 + px) * 32 + oc] = acc[n][r] + bv;
        }
    }
}

// ---------------------------------------------------------------- im2col sampler
// block = 8 px x 9 taps x 128 ch. Pure streaming: no MFMA, no K-loop barriers,
// 8 blocks/CU-class occupancy. Writes Aim[pix_local][tap*128+c] f16.
__global__ __launch_bounds__(256) void sample_a(const unsigned short* __restrict__ inh,
                                                const float* __restrict__ wi32,
                                                unsigned short* __restrict__ Aim,
                                                int pixbase) {
    __shared__ __align__(16) uint4 offs[8][9];
    __shared__ __align__(16) uint2 wgts[8][9];

    int t   = threadIdx.x;
    int bid = blockIdx.x;
    int lg  = ((bid & 7) << 8) | (bid >> 3);      // 2048 = 8*256, XCD-bijective
    int pix0 = pixbase + (lg << 3);               // global pixel of this block
    int loc0 = lg << 3;                           // local Aim row

    // ---- params: 72 items
    if (t < 72) {
        int pxl = t / 9, tap = t - pxl * 9;
        int pix = pix0 + pxl;
        int bb  = pix >> 12;
        int hh  = (pix >> 6) & 63;
        int col = pix & 63;
        const float* wp = wi32 + (size_t)pix * 32;
        float o1 = wp[tap], o2 = wp[9 + tap], mm = wp[18 + tap];
        float mask = 1.f / (1.f + __expf(-mm));
        int ky = tap / 3, kx = tap - ky * 3;
        float py  = (float)(hh - 1 + ky) + o1;
        float pxx = (float)(col - 1 + kx) + o2;
        float y0f = floorf(py), x0f = floorf(pxx);
        float wy1 = py - y0f,  wy0 = 1.f - wy1;
        float wx1 = pxx - x0f, wx0 = 1.f - wx1;
        float vy0 = (y0f >=  0.f && y0f <= 63.f) ? 1.f : 0.f;
        float vy1 = (y0f >= -1.f && y0f <= 62.f) ? 1.f : 0.f;
        float vx0 = (x0f >=  0.f && x0f <= 63.f) ? 1.f : 0.f;
        float vx1 = (x0f >= -1.f && x0f <= 62.f) ? 1.f : 0.f;
        int y0 = (int)fminf(fmaxf(y0f,       0.f), 63.f);
        int y1 = (int)fminf(fmaxf(y0f + 1.f, 0.f), 63.f);
        int x0 = (int)fminf(fmaxf(x0f,       0.f), 63.f);
        int x1 = (int)fminf(fmaxf(x0f + 1.f, 0.f), 63.f);
        int base = bb << 12;
        offs[pxl][tap] = make_uint4((unsigned)((base + (y0 << 6) + x0) << 8),
                                    (unsigned)((base + (y0 << 6) + x1) << 8),
                                    (unsigned)((base + (y1 << 6) + x0) << 8),
                                    (unsigned)((base + (y1 << 6) + x1) << 8));
        wgts[pxl][tap] = make_uint2(pkh2(wy0 * wx0 * mask * vy0 * vx0,
                                         wy0 * wx1 * mask * vy0 * vx1),
                                    pkh2(wy1 * wx0 * mask * vy1 * vx0,
                                         wy1 * wx1 * mask * vy1 * vx1));
    }
    __syncthreads();

    int c8  = t & 15;
    int pxl = (t >> 4) & 7;
    int th  = t >> 7;                 // 0: taps 0..4, 1: taps 5..8
    int cb  = c8 << 4;

    const char* ih = (const char*)inh;
    char* Ao = (char*)Aim + (size_t)(loc0 + pxl) * 2304;

    int tbeg = th ? 5 : 0, tend = th ? 9 : 5;
    union AU { uint4 u; __half2 h[4]; };
    #pragma unroll 5
    for (int tap = tbeg; tap < tend; ++tap) {
        uint4 O  = offs[pxl][tap];
        uint2 Wp = wgts[pxl][tap];
        union { unsigned u; __half2 h; } w00, w01, w10, w11;
        w00.u = (Wp.x & 0xFFFFu) * 0x10001u;
        w01.u = (Wp.x >> 16)     * 0x10001u;
        w10.u = (Wp.y & 0xFFFFu) * 0x10001u;
        w11.u = (Wp.y >> 16)     * 0x10001u;
        AU c00, c01, c10, c11, s;
        c00.u = *(const uint4*)(ih + O.x + cb);
        c01.u = *(const uint4*)(ih + O.y + cb);
        c10.u = *(const uint4*)(ih + O.z + cb);
        c11.u = *(const uint4*)(ih + O.w + cb);
        #pragma unroll
        for (int j = 0; j < 4; ++j) {
            __half2 sj = __hmul2(c00.h[j], w00.h);
            sj = __hfma2(c01.h[j], w01.h, sj);
            sj = __hfma2(c10.h[j], w10.h, sj);
            s.h[j] = __hfma2(c11.h[j], w11.h, sj);
        }
        *(uint4*)(Ao + tap * 256 + cb) = s.u;
    }
}

// ---------------------------------------------------------------- im2col GEMM (m97 recipe)
// C[16384 x 256] (half) = Aim[16384 x 1152] * filtT2^T. 128x128 tile, BK=64,
// global_load_lds w16, T2 source-pre-swizzle, 2-barrier K-loop.
__global__ __launch_bounds__(256) void gemm_im2col(const unsigned short* __restrict__ Aim,
                                                   const unsigned short* __restrict__ filtT2,
                                                   float* __restrict__ out,
                                                   int pixbase) {
    __shared__ __align__(16) unsigned char As[16384];   // [128 rows][128 B], swizzled
    __shared__ __align__(16) unsigned char Bs[16384];

    int t   = threadIdx.x;
    int bid = blockIdx.x;
    int lg  = ((bid & 7) << 5) | (bid >> 3);      // 256 = 8*32, XCD-bijective
    int mt  = lg >> 1, nt = lg & 1;
    int apix = mt << 7;                            // local A row base
    int f0   = nt << 7;

    int lane = t & 63, wv = t >> 6;
    int wm = wv & 1, wn = wv >> 1;
    int row16 = lane & 15, kg = lane >> 4;

    const char* Ab = (const char*)Aim;
    const char* Bb = (const char*)filtT2;

    f32x4 z = {0.f, 0.f, 0.f, 0.f};
    f32x4 acc[4][4];
    #pragma unroll
    for (int m = 0; m < 4; ++m)
        #pragma unroll
        for (int n = 0; n < 4; ++n) acc[m][n] = z;

    // staging geometry (per lane, loop-invariant)
    int lin0 = wv * 1024 + lane * 16;

    for (int kb = 0; kb < 18; ++kb) {
        int k2 = kb << 7;                          // byte offset along k
        #pragma unroll
        for (int it = 0; it < 4; ++it) {
            int lin  = lin0 + it * 4096;
            int arow = lin >> 7;
            int acol = (lin & 127) ^ ((arow & 7) << 4);
            async16(As + wv * 1024 + it * 4096,
                    Ab + (size_t)(apix + arow) * 2304 + k2 + acol);
            async16(Bs + wv * 1024 + it * 4096,
                    Bb + (size_t)(f0 + arow) * 2304 + k2 + acol);
        }
        __syncthreads();                           // drains vmcnt, tiles ready

        int sw = (row16 & 7) << 4;
        #pragma unroll
        for (int ks = 0; ks < 2; ++ks) {
            int kcol = ((ks << 6) + (kg << 4)) ^ sw;
            f16x8 a[4], b[4];
            #pragma unroll
            for (int m = 0; m < 4; ++m)
                a[m] = *(const f16x8*)(As + ((wm << 6) + (m << 4) + row16) * 128 + kcol);
            #pragma unroll
            for (int n = 0; n < 4; ++n)
                b[n] = *(const f16x8*)(Bs + ((wn << 6) + (n << 4) + row16) * 128 + kcol);
            #pragma unroll
            for (int m = 0; m < 4; ++m)
                #pragma unroll
                for (int n = 0; n < 4; ++n)
                    acc[m][n] = __builtin_amdgcn_mfma_f32_16x16x32_f16(a[m], b[n], acc[m][n], 0, 0, 0);
        }
        __syncthreads();                           // compute done before restage
    }

    // epilogue: px = m*16 + 4*kg + r, f = n*16 + row16
    int pxb = pixbase + apix + (wm << 6);
    int fcb = f0 + (wn << 6) + row16;
    #pragma unroll
    for (int m = 0; m < 4; ++m)
        #pragma unroll
        for (int r = 0; r < 4; ++r) {
            int px = pxb + (m << 4) + (kg << 2) + r;
            float* op = out + (size_t)px * 256 + fcb;
            op[0]  = acc[m][0][r];
            op[16] = acc[m][1][r];
            op[32] = acc[m][2][r];
            op[48] = acc[m][3][r];
        }
}

// ---------------------------------------------------------------- launch
extern "C" void kernel_launch(void* const* d_in, const int* in_sizes, int n_in,
                              void* d_out, int out_size, void* d_ws, size_t ws_size,
                              hipStream_t stream) {
    const float* in   = (const float*)d_in[0];
    const float* kofs = (const float*)d_in[1];
    const float* bias = (const float*)d_in[2];
    const float* filt = (const float*)d_in[3];
    float* out = (float*)d_out;
    float* ws  = (float*)d_ws;

    unsigned short* woffT  = (unsigned short*)ws;
    unsigned short* filtT2 = (unsigned short*)(ws + FILTT_OFF_F);
    float*          wi32   = ws + WI32_OFF_F;
    unsigned short* inh    = (unsigned short*)(ws + INH_OFF_F);
    unsigned short* Aim    = (unsigned short*)(ws + AIM_OFF_F);

    hipLaunchKernelGGL(repack, dim3(1296), dim3(256), 0, stream, kofs, filt, woffT, filtT2);
    hipLaunchKernelGGL(conv_f16, dim3(1024), dim3(256), 0, stream, in, inh);
    hipLaunchKernelGGL(offset_conv_mfma, dim3(512), dim3(256), 0, stream, inh, woffT, bias, wi32);
    for (int half = 0; half < 2; ++half) {
        int pixbase = half * 16384;
        hipLaunchKernelGGL(sample_a, dim3(2048), dim3(256), 0, stream, inh, wi32, Aim, pixbase);
        hipLaunchKernelGGL(gemm_im2col, dim3(256), dim3(256), 0, stream, Aim, filtT2, out, pixbase);
    }
}

// Round 9
// 76.784 us; speedup vs baseline: 2.8804x; 1.3993x over previous
//
#include <hip/hip_runtime.h>
#include <hip/hip_fp16.h>
#include <math.h>

#define B_  8
#define H_  64
#define W_  64
#define C_  128
#define F_  256
#define NOC 27

typedef float    f32x4 __attribute__((ext_vector_type(4)));
typedef _Float16 f16x8 __attribute__((ext_vector_type(8)));

// ws layout (float units):
//   woffT  : f16[9][32][128]     @ 0        (73728 B)
//   filtT2 : f16[256][1152]      @ 32768    (589824 B)   [f][k], k=tap*128+c
//   wi32   : float[32768][32]    @ 180224   (4 MB)
//   inh    : f16[8][64][64][128] @ 1228800  (8.4 MB)
//   Aim    : f16[32768][1152]    @ 3325952  (75.5 MB)    im2col full image
// total ~89 MB of d_ws (~268 MB available)
#define FILTT_OFF_F 32768
#define WI32_OFF_F  180224
#define INH_OFF_F   1228800
#define AIM_OFF_F   3325952

static __device__ __forceinline__ unsigned pkh2(float a, float b) {
    __half2 h = __floats2half2_rn(a, b);
    union { __half2 h2; unsigned u; } cv; cv.h2 = h;
    return cv.u;
}

static __device__ __forceinline__ void async16(void* lds, const void* g) {
    __builtin_amdgcn_global_load_lds(
        (const __attribute__((address_space(1))) unsigned int*)g,
        (__attribute__((address_space(3))) unsigned int*)lds, 16, 0, 0);
}

// ---------------------------------------------------------------- prep:
// blocks [0,1296): repack weights; blocks [1296,2320): input f32->f16
__global__ __launch_bounds__(256) void prep(const float* __restrict__ kofs,
                                            const float* __restrict__ filt,
                                            const float* __restrict__ in,
                                            unsigned short* __restrict__ woffT,
                                            unsigned short* __restrict__ filtT2,
                                            unsigned short* __restrict__ inh) {
    int bidx = blockIdx.x;
    if (bidx >= 1296) {
        int gid = (bidx - 1296) * 256 + threadIdx.x;
        const float4* ip = reinterpret_cast<const float4*>(in) + (size_t)gid * 4;
        float4 a = ip[0], b = ip[1], c = ip[2], d = ip[3];
        uint4 r0 = make_uint4(pkh2(a.x, a.y), pkh2(a.z, a.w), pkh2(b.x, b.y), pkh2(b.z, b.w));
        uint4 r1 = make_uint4(pkh2(c.x, c.y), pkh2(c.z, c.w), pkh2(d.x, d.y), pkh2(d.z, d.w));
        uint4* op = reinterpret_cast<uint4*>(inh) + (size_t)gid * 2;
        op[0] = r0; op[1] = r1;
        return;
    }
    int idx = bidx * 256 + threadIdx.x;
    if (idx < 9 * 32 * 128) {
        int tap = idx >> 12;
        int r   = idx & 4095;
        int oc  = r >> 7;
        int c   = r & 127;
        float v = (oc < NOC) ? kofs[(tap * C_ + c) * NOC + oc] : 0.f;
        union { __half h; unsigned short u; } cv; cv.h = __float2half(v);
        woffT[idx] = cv.u;
        return;
    }
    int idx2 = idx - 9 * 32 * 128;
    if (idx2 < 9 * 256 * 128) {
        int tap = idx2 / 32768;
        int r   = idx2 & 32767;
        int f   = r >> 7;
        int c   = r & 127;
        float v = filt[(tap * C_ + c) * F_ + f];
        union { __half h; unsigned short u; } cv; cv.h = __float2half(v);
        filtT2[(size_t)f * 1152 + tap * 128 + c] = cv.u;
    }
}

// ---------------------------------------------------------------- offset conv (f16 MFMA)
__global__ __launch_bounds__(256) void offset_conv_mfma(const unsigned short* __restrict__ inh,
                                                        const unsigned short* __restrict__ woffT,
                                                        const float* __restrict__ bias,
                                                        float* __restrict__ wi32) {
    __shared__ __align__(16) unsigned char win[3 * 66 * 256];   // 50688 B

    int t    = threadIdx.x;
    int bid  = blockIdx.x;
    int lg   = ((bid & 7) << 6) | (bid >> 3);       // 512 = 8*64
    int bb   = lg >> 6;
    int hh   = lg & 63;
    int pix0 = lg << 6;

    for (int idx = t; idx < 3 * 66 * 16; idx += 256) {
        int ky = idx / (66 * 16);
        int r  = idx % (66 * 16);
        int xi = r >> 4;
        int c8 = r & 15;
        int y  = hh + ky - 1;
        int x  = xi - 1;
        uint4 v = make_uint4(0u, 0u, 0u, 0u);
        if ((unsigned)y < 64u && (unsigned)x < 64u)
            v = *(const uint4*)((const char*)inh +
                    ((size_t)(((bb << 6) + y) * 64 + x) << 8) + (c8 << 4));
        *(uint4*)(win + ky * 16896 + xi * 256 + ((c8 << 4) ^ ((xi & 7) << 4))) = v;
    }
    __syncthreads();

    int lane = t & 63, wv = t >> 6;
    int row  = lane & 15, kg = lane >> 4;
    int px0  = wv << 4;

    f32x4 z = {0.f, 0.f, 0.f, 0.f};
    f32x4 acc[2] = {z, z};

    for (int tap = 0; tap < 9; ++tap) {
        int ky = tap / 3, kx = tap - ky * 3;
        int xi = px0 + row + kx;
        const unsigned char* arow = win + ky * 16896 + xi * 256;
        int sw = (xi & 7) << 4;
        const unsigned short* bp = woffT + (size_t)tap * 4096 + (size_t)row * 128 + kg * 8;
        #pragma unroll
        for (int ks = 0; ks < 4; ++ks) {
            f16x8 a  = *(const f16x8*)(arow + ((ks * 64 + kg * 16) ^ sw));
            f16x8 b0 = *(const f16x8*)(bp + ks * 32);
            f16x8 b1 = *(const f16x8*)(bp + 2048 + ks * 32);
            acc[0] = __builtin_amdgcn_mfma_f32_16x16x32_f16(a, b0, acc[0], 0, 0, 0);
            acc[1] = __builtin_amdgcn_mfma_f32_16x16x32_f16(a, b1, acc[1], 0, 0, 0);
        }
    }

    #pragma unroll
    for (int n = 0; n < 2; ++n) {
        int oc = n * 16 + row;
        float bv = (oc < NOC) ? bias[oc] : 0.f;
        #pragma unroll
        for (int r = 0; r < 4; ++r) {
            int px = px0 + kg * 4 + r;
            wi32[(size_t)(pix0 + px) * 32 + oc] = acc[n][r] + bv;
        }
    }
}

// ---------------------------------------------------------------- im2col sampler
// block = 8 px x 9 taps x 128 ch, full image (grid 4096). Pure streaming.
__global__ __launch_bounds__(256) void sample_a(const unsigned short* __restrict__ inh,
                                                const float* __restrict__ wi32,
                                                unsigned short* __restrict__ Aim) {
    __shared__ __align__(16) uint4 offs[8][9];
    __shared__ __align__(16) uint2 wgts[8][9];

    int t   = threadIdx.x;
    int bid = blockIdx.x;
    int lg  = ((bid & 7) << 9) | (bid >> 3);      // 4096 = 8*512, XCD-bijective
    int pix0 = lg << 3;

    if (t < 72) {
        int pxl = t / 9, tap = t - pxl * 9;
        int pix = pix0 + pxl;
        int bb  = pix >> 12;
        int hh  = (pix >> 6) & 63;
        int col = pix & 63;
        const float* wp = wi32 + (size_t)pix * 32;
        float o1 = wp[tap], o2 = wp[9 + tap], mm = wp[18 + tap];
        float mask = 1.f / (1.f + __expf(-mm));
        int ky = tap / 3, kx = tap - ky * 3;
        float py  = (float)(hh - 1 + ky) + o1;
        float pxx = (float)(col - 1 + kx) + o2;
        float y0f = floorf(py), x0f = floorf(pxx);
        float wy1 = py - y0f,  wy0 = 1.f - wy1;
        float wx1 = pxx - x0f, wx0 = 1.f - wx1;
        float vy0 = (y0f >=  0.f && y0f <= 63.f) ? 1.f : 0.f;
        float vy1 = (y0f >= -1.f && y0f <= 62.f) ? 1.f : 0.f;
        float vx0 = (x0f >=  0.f && x0f <= 63.f) ? 1.f : 0.f;
        float vx1 = (x0f >= -1.f && x0f <= 62.f) ? 1.f : 0.f;
        int y0 = (int)fminf(fmaxf(y0f,       0.f), 63.f);
        int y1 = (int)fminf(fmaxf(y0f + 1.f, 0.f), 63.f);
        int x0 = (int)fminf(fmaxf(x0f,       0.f), 63.f);
        int x1 = (int)fminf(fmaxf(x0f + 1.f, 0.f), 63.f);
        int base = bb << 12;
        offs[pxl][tap] = make_uint4((unsigned)((base + (y0 << 6) + x0) << 8),
                                    (unsigned)((base + (y0 << 6) + x1) << 8),
                                    (unsigned)((base + (y1 << 6) + x0) << 8),
                                    (unsigned)((base + (y1 << 6) + x1) << 8));
        wgts[pxl][tap] = make_uint2(pkh2(wy0 * wx0 * mask * vy0 * vx0,
                                         wy0 * wx1 * mask * vy0 * vx1),
                                    pkh2(wy1 * wx0 * mask * vy1 * vx0,
                                         wy1 * wx1 * mask * vy1 * vx1));
    }
    __syncthreads();

    int c8  = t & 15;
    int pxl = (t >> 4) & 7;
    int th  = t >> 7;                 // 0: taps 0..4, 1: taps 5..8
    int cb  = c8 << 4;

    const char* ih = (const char*)inh;
    char* Ao = (char*)Aim + (size_t)(pix0 + pxl) * 2304;

    int tbeg = th ? 5 : 0, tend = th ? 9 : 5;
    union AU { uint4 u; __half2 h[4]; };
    #pragma unroll 5
    for (int tap = tbeg; tap < tend; ++tap) {
        uint4 O  = offs[pxl][tap];
        uint2 Wp = wgts[pxl][tap];
        union { unsigned u; __half2 h; } w00, w01, w10, w11;
        w00.u = (Wp.x & 0xFFFFu) * 0x10001u;
        w01.u = (Wp.x >> 16)     * 0x10001u;
        w10.u = (Wp.y & 0xFFFFu) * 0x10001u;
        w11.u = (Wp.y >> 16)     * 0x10001u;
        AU c00, c01, c10, c11, s;
        c00.u = *(const uint4*)(ih + O.x + cb);
        c01.u = *(const uint4*)(ih + O.y + cb);
        c10.u = *(const uint4*)(ih + O.z + cb);
        c11.u = *(const uint4*)(ih + O.w + cb);
        #pragma unroll
        for (int j = 0; j < 4; ++j) {
            __half2 sj = __hmul2(c00.h[j], w00.h);
            sj = __hfma2(c01.h[j], w01.h, sj);
            sj = __hfma2(c10.h[j], w10.h, sj);
            s.h[j] = __hfma2(c11.h[j], w11.h, sj);
        }
        *(uint4*)(Ao + tap * 256 + cb) = s.u;
    }
}

// ---------------------------------------------------------------- im2col GEMM (m97 recipe)
// C[32768 x 256] = Aim[32768 x 1152] * filtT2^T. 128x128 tile, BK=64,
// global_load_lds w16, T2 source-pre-swizzle, 2-barrier K-loop. grid 512.
__global__ __launch_bounds__(256) void gemm_im2col(const unsigned short* __restrict__ Aim,
                                                   const unsigned short* __restrict__ filtT2,
                                                   float* __restrict__ out) {
    __shared__ __align__(16) unsigned char As[16384];   // [128 rows][128 B], swizzled
    __shared__ __align__(16) unsigned char Bs[16384];

    int t   = threadIdx.x;
    int bid = blockIdx.x;
    int lg  = ((bid & 7) << 6) | (bid >> 3);      // 512 = 8*64, XCD-bijective
    int mt  = lg >> 1, nt = lg & 1;
    int apix = mt << 7;
    int f0   = nt << 7;

    int lane = t & 63, wv = t >> 6;
    int wm = wv & 1, wn = wv >> 1;
    int row16 = lane & 15, kg = lane >> 4;

    const char* Ab = (const char*)Aim;
    const char* Bb = (const char*)filtT2;

    f32x4 z = {0.f, 0.f, 0.f, 0.f};
    f32x4 acc[4][4];
    #pragma unroll
    for (int m = 0; m < 4; ++m)
        #pragma unroll
        for (int n = 0; n < 4; ++n) acc[m][n] = z;

    int lin0 = wv * 1024 + lane * 16;

    for (int kb = 0; kb < 18; ++kb) {
        int k2 = kb << 7;
        #pragma unroll
        for (int it = 0; it < 4; ++it) {
            int lin  = lin0 + it * 4096;
            int arow = lin >> 7;
            int acol = (lin & 127) ^ ((arow & 7) << 4);
            async16(As + wv * 1024 + it * 4096,
                    Ab + (size_t)(apix + arow) * 2304 + k2 + acol);
            async16(Bs + wv * 1024 + it * 4096,
                    Bb + (size_t)(f0 + arow) * 2304 + k2 + acol);
        }
        __syncthreads();

        int sw = (row16 & 7) << 4;
        #pragma unroll
        for (int ks = 0; ks < 2; ++ks) {
            int kcol = ((ks << 6) + (kg << 4)) ^ sw;
            f16x8 a[4], b[4];
            #pragma unroll
            for (int m = 0; m < 4; ++m)
                a[m] = *(const f16x8*)(As + ((wm << 6) + (m << 4) + row16) * 128 + kcol);
            #pragma unroll
            for (int n = 0; n < 4; ++n)
                b[n] = *(const f16x8*)(Bs + ((wn << 6) + (n << 4) + row16) * 128 + kcol);
            #pragma unroll
            for (int m = 0; m < 4; ++m)
                #pragma unroll
                for (int n = 0; n < 4; ++n)
                    acc[m][n] = __builtin_amdgcn_mfma_f32_16x16x32_f16(a[m], b[n], acc[m][n], 0, 0, 0);
        }
        __syncthreads();
    }

    int pxb = apix + (wm << 6);
    int fcb = f0 + (wn << 6) + row16;
    #pragma unroll
    for (int m = 0; m < 4; ++m)
        #pragma unroll
        for (int r = 0; r < 4; ++r) {
            int px = pxb + (m << 4) + (kg << 2) + r;
            float* op = out + (size_t)px * 256 + fcb;
            op[0]  = acc[m][0][r];
            op[16] = acc[m][1][r];
            op[32] = acc[m][2][r];
            op[48] = acc[m][3][r];
        }
}

// ---------------------------------------------------------------- launch
extern "C" void kernel_launch(void* const* d_in, const int* in_sizes, int n_in,
                              void* d_out, int out_size, void* d_ws, size_t ws_size,
                              hipStream_t stream) {
    const float* in   = (const float*)d_in[0];
    const float* kofs = (const float*)d_in[1];
    const float* bias = (const float*)d_in[2];
    const float* filt = (const float*)d_in[3];
    float* out = (float*)d_out;
    float* ws  = (float*)d_ws;

    unsigned short* woffT  = (unsigned short*)ws;
    unsigned short* filtT2 = (unsigned short*)(ws + FILTT_OFF_F);
    float*          wi32   = ws + WI32_OFF_F;
    unsigned short* inh    = (unsigned short*)(ws + INH_OFF_F);
    unsigned short* Aim    = (unsigned short*)(ws + AIM_OFF_F);

    hipLaunchKernelGGL(prep, dim3(2320), dim3(256), 0, stream, kofs, filt, in, woffT, filtT2, inh);
    hipLaunchKernelGGL(offset_conv_mfma, dim3(512), dim3(256), 0, stream, inh, woffT, bias, wi32);
    hipLaunchKernelGGL(sample_a, dim3(4096), dim3(256), 0, stream, inh, wi32, Aim);
    hipLaunchKernelGGL(gemm_im2col, dim3(512), dim3(256), 0, stream, Aim, filtT2, out);
}